// Round 4
// baseline (1542.576 us; speedup 1.0000x reference)
//
#include <hip/hip_runtime.h>

// ---------------------------------------------------------------------------
// Sememe-LSTM, MI355X (gfx950).
// pack_act/pack_w: fp32 -> (hi,lo) bf16 split, pre-swizzled LDS-shaped tiles.
// gemm_mfma: 128x128 split-bf16 MFMA GEMM (3-product => fp32-grade), fused
//   bias/sigmoid epilogue, transposed streams.
// lstm_rec (round-4 redesign): 4 groups(16 b) x 16 wgs(32 m, 512 thr).
//   h exchanged as packed (hi<<16|lo) dwords whose lo-LSB carries a 1-bit
//   epoch tag => readers poll the DATA itself (no flags, no store-ack, no
//   separate barrier). Buffers alternate by t&1; same-buffer epochs differ
//   by 2 steps => opposite tag. Init: buf0=0x00 (valid h0=0), buf1=0x01
//   (stale-marked). Round-3 PMC showed 97% stall = ~4.5 MALL round trips
//   per step; this protocol needs ~1-2.
// ---------------------------------------------------------------------------

#define T_STEPS 256
#define BATCH   64
#define MEM     512
#define ROWS    16384

typedef __attribute__((ext_vector_type(8))) short bf16x8;
typedef __attribute__((ext_vector_type(4))) short short4v;
typedef __attribute__((ext_vector_type(4))) float f32x4;
typedef __attribute__((ext_vector_type(4))) unsigned int u32x4;

__device__ __forceinline__ short f2bf(float x) {
  unsigned u = __builtin_bit_cast(unsigned, x);
  u = u + 0x7fffu + ((u >> 16) & 1u);   // RNE to bf16
  return (short)(u >> 16);
}
__device__ __forceinline__ float bf2f(short s) {
  unsigned u = ((unsigned)(unsigned short)s) << 16;
  return __builtin_bit_cast(float, u);
}
__device__ __forceinline__ float sigmoidf_(float x) { return 1.f / (1.f + expf(-x)); }

// MALL-coherent (sc0 sc1) ops — cross-XCD safe without cache-maintenance fences.
__device__ __forceinline__ u32x4 load16_sc(const void* p) {
  u32x4 r;
  asm volatile("global_load_dwordx4 %0, %1, off sc0 sc1" : "=v"(r) : "v"(p) : "memory");
  return r;
}
__device__ __forceinline__ void store4_sc(void* p, unsigned v) {
  asm volatile("global_store_dword %0, %1, off sc0 sc1" :: "v"(p), "v"(v) : "memory");
}

// ---------------------------------------------------------------------------
// pack_act: inputs/sememe_h [16384][512] f32 -> Apack tiles (swizzled).
// ---------------------------------------------------------------------------
__global__ __launch_bounds__(256) void pack_act(
    const float* __restrict__ inputs, const float* __restrict__ sememe_h,
    char* __restrict__ Apack)
{
  int gid = blockIdx.x * 256 + threadIdx.x;
  int sel = gid >> 20;
  int rem = gid & 1048575;
  int R = rem >> 6, kg = rem & 63;
  const float* src = (sel ? sememe_h : inputs) + (size_t)R * 512 + kg * 8;
  float4 a = *(const float4*)src;
  float4 b = *(const float4*)(src + 4);
  float v[8] = {a.x, a.y, a.z, a.w, b.x, b.y, b.z, b.w};
  bf16x8 hi8, lo8;
#pragma unroll
  for (int e = 0; e < 8; ++e) {
    short h = f2bf(v[e]);
    hi8[e] = h;
    lo8[e] = f2bf(v[e] - bf2f(h));
  }
  int rt = R >> 7, r = R & 127, kt = sel * 16 + (kg >> 2), ls = kg & 3;
  char* rowp = Apack + ((size_t)((rt * 32 + kt) * 128 + r)) * 128;
  *(bf16x8*)(rowp + ((ls ^ (r & 7)) << 4))       = hi8;
  *(bf16x8*)(rowp + (((4 + ls) ^ (r & 7)) << 4)) = lo8;
}

// ---------------------------------------------------------------------------
// pack_w: weights -> Wpack tiles (swizzled by output-col).
// ---------------------------------------------------------------------------
__global__ __launch_bounds__(256) void pack_w(
    const float* __restrict__ W_ioux, const float* __restrict__ W_ious,
    const float* __restrict__ W_fx,   const float* __restrict__ W_fxs,
    const float* __restrict__ W_fs,   char* __restrict__ Wpack)
{
  int gid = blockIdx.x * 256 + threadIdx.x;
  if (gid >= 20 * 32 * 128 * 4) return;
  int ct = gid >> 14;
  int rem = gid & 16383;
  int ktv = rem >> 9;
  int rem2 = rem & 511;
  int cc = rem2 >> 2, kg = rem2 & 3;
  int region = (ct < 12) ? 0 : (ct < 16 ? 1 : 2);
  if (region == 1 && ktv >= 16) return;
  const float* srcrow;
  int k0;
  if (region == 0) {
    int c = ct * 128 + cc;
    if (ktv < 16) { srcrow = W_ioux + (size_t)c * 512; k0 = ktv * 32 + kg * 8; }
    else          { srcrow = W_ious + (size_t)c * 512; k0 = (ktv - 16) * 32 + kg * 8; }
  } else if (region == 1) {
    int c = (ct - 12) * 128 + cc;
    srcrow = W_fx + (size_t)c * 512; k0 = ktv * 32 + kg * 8;
  } else {
    int c = (ct - 16) * 128 + cc;
    if (ktv < 16) { srcrow = W_fxs + (size_t)c * 512; k0 = ktv * 32 + kg * 8; }
    else          { srcrow = W_fs  + (size_t)c * 512; k0 = (ktv - 16) * 32 + kg * 8; }
  }
  float4 a = *(const float4*)(srcrow + k0);
  float4 b = *(const float4*)(srcrow + k0 + 4);
  float v[8] = {a.x, a.y, a.z, a.w, b.x, b.y, b.z, b.w};
  bf16x8 hi8, lo8;
#pragma unroll
  for (int e = 0; e < 8; ++e) {
    short h = f2bf(v[e]);
    hi8[e] = h;
    lo8[e] = f2bf(v[e] - bf2f(h));
  }
  char* rowp = Wpack + ((size_t)((ct * 32 + ktv) * 128 + cc)) * 128;
  *(bf16x8*)(rowp + ((kg ^ (cc & 7)) << 4))       = hi8;
  *(bf16x8*)(rowp + (((4 + kg) ^ (cc & 7)) << 4)) = lo8;
}

// ---------------------------------------------------------------------------
// gemm_mfma: 128x128 tile, 4 waves 2x2, 16x16x32 bf16, 3-product split.
// ---------------------------------------------------------------------------
#define GLL(gsrc, ldst) __builtin_amdgcn_global_load_lds( \
    (const __attribute__((address_space(1))) unsigned*)(gsrc), \
    (__attribute__((address_space(3))) unsigned*)(ldst), 16, 0, 0)

__global__ __launch_bounds__(256, 2) void gemm_mfma(
    const char* __restrict__ Apack, const char* __restrict__ Wpack,
    const float* __restrict__ sememe_c,
    const float* __restrict__ b_ioux, const float* __restrict__ b_iouh,
    const float* __restrict__ b_ious, const float* __restrict__ b_fx,
    const float* __restrict__ b_fh,  const float* __restrict__ b_fxs,
    const float* __restrict__ b_fs,
    float* __restrict__ iouT, float* __restrict__ fxT, float* __restrict__ fscT)
{
  __shared__ char ldsb[65536];
  __shared__ float bsum[128];

  const int bx = blockIdx.x;
  const int swz = (bx & 7) * 320 + (bx >> 3);
  const int rt = swz / 20, ct = swz % 20;
  const int tid = threadIdx.x, lane = tid & 63, wv = tid >> 6;
  const int wm = wv >> 1, wn = wv & 1;
  const int l15 = lane & 15, kgrp = lane >> 4;

  const int region = (ct < 12) ? 0 : (ct < 16 ? 1 : 2);
  const int cb0 = (region == 0) ? ct * 128 : (region == 1 ? (ct - 12) * 128 : (ct - 16) * 128);
  const int nkt = (region == 1) ? 16 : 32;

  if (tid < 128) {
    int c = cb0 + tid;
    bsum[tid] = (region == 0) ? b_ioux[c] + b_ious[c] + b_iouh[c]
              : (region == 1) ? b_fx[c] + b_fh[c]
                              : b_fxs[c] + b_fs[c];
  }

  const char* Ablk0 = Apack + (size_t)rt * 32 * 16384;
  const char* Wblk0 = Wpack + (size_t)ct * 32 * 16384;

  int aoffH[4], aoffL[4], boffH[4], boffL[4];
#pragma unroll
  for (int f = 0; f < 4; ++f) {
    int c_loc = wm * 64 + f * 16 + l15;
    aoffH[f] = c_loc * 128 + ((kgrp ^ (c_loc & 7)) << 4);
    aoffL[f] = c_loc * 128 + (((4 + kgrp) ^ (c_loc & 7)) << 4);
    int r_loc = wn * 64 + f * 16 + l15;
    boffH[f] = r_loc * 128 + ((kgrp ^ (r_loc & 7)) << 4);
    boffL[f] = r_loc * 128 + (((4 + kgrp) ^ (r_loc & 7)) << 4);
  }

#define STAGE(ktv, buf) do { \
    const char* As_ = Ablk0 + (size_t)(ktv) * 16384; \
    const char* Ws_ = Wblk0 + (size_t)(ktv) * 16384; \
    char* Ld_ = ldsb + (buf) * 32768; \
    _Pragma("unroll") \
    for (int i_ = 0; i_ < 4; ++i_) { \
      int off_ = (wv * 4 + i_) * 1024; \
      GLL(Ws_ + off_ + lane * 16, Ld_ + off_); \
      GLL(As_ + off_ + lane * 16, Ld_ + 16384 + off_); \
    } } while (0)

  f32x4 acc[4][4];
#pragma unroll
  for (int a = 0; a < 4; ++a)
#pragma unroll
    for (int b = 0; b < 4; ++b) acc[a][b] = (f32x4){0.f, 0.f, 0.f, 0.f};

  STAGE(0, 0);
  asm volatile("s_waitcnt vmcnt(0)" ::: "memory");
  __syncthreads();

  for (int kt = 0; kt < nkt; ++kt) {
    const int cur = kt & 1;
    if (kt + 1 < nkt) STAGE(kt + 1, cur ^ 1);
    const char* Wt = ldsb + cur * 32768;
    const char* At = Wt + 16384;
    bf16x8 AH[4], AL[4], BH[4], BL[4];
#pragma unroll
    for (int f = 0; f < 4; ++f) {
      AH[f] = *(const bf16x8*)(Wt + aoffH[f]);
      AL[f] = *(const bf16x8*)(Wt + aoffL[f]);
      BH[f] = *(const bf16x8*)(At + boffH[f]);
      BL[f] = *(const bf16x8*)(At + boffL[f]);
    }
#pragma unroll
    for (int fm = 0; fm < 4; ++fm)
#pragma unroll
      for (int fn = 0; fn < 4; ++fn) {
        acc[fm][fn] = __builtin_amdgcn_mfma_f32_16x16x32_bf16(AH[fm], BH[fn], acc[fm][fn], 0, 0, 0);
        acc[fm][fn] = __builtin_amdgcn_mfma_f32_16x16x32_bf16(AH[fm], BL[fn], acc[fm][fn], 0, 0, 0);
        acc[fm][fn] = __builtin_amdgcn_mfma_f32_16x16x32_bf16(AL[fm], BH[fn], acc[fm][fn], 0, 0, 0);
      }
    asm volatile("s_waitcnt vmcnt(0)" ::: "memory");
    __syncthreads();
  }

  const int r0 = rt * 128;
  float* stream = (region == 0) ? iouT : (region == 1) ? fxT : fscT;
#pragma unroll
  for (int fm = 0; fm < 4; ++fm)
#pragma unroll
    for (int fn = 0; fn < 4; ++fn) {
      int rr = r0 + wn * 64 + fn * 16 + l15;
#pragma unroll
      for (int i = 0; i < 4; ++i) {
        int c_loc = wm * 64 + fm * 16 + kgrp * 4 + i;
        float val = acc[fm][fn][i] + bsum[c_loc];
        if (region == 2)
          val = sigmoidf_(val) * sememe_c[(size_t)rr * MEM + cb0 + c_loc];
        stream[(size_t)(cb0 + c_loc) * ROWS + rr] = val;
      }
    }
}

// ---------------------------------------------------------------------------
// lstm_rec: 64 wgs x 512 thr = 4 groups(16 b) x 16 wgs(32 m).
// Waves: gate = wv&3 (i,o,u,f), half = wv>>2 (m 0-15 / 16-31).
// hplane dwords, buf-major: [buf 0/1][group 0..3][16 b][512 m].
//   dword = (hi16<<16) | (lo16 & ~1) | epochTag, tag(t) = (t>>1)&1 for the
//   buffer read at step t. Poll = tagged data load; no flags, no acks.
// ---------------------------------------------------------------------------
__global__ __launch_bounds__(512, 1) void lstm_rec(
    const float* __restrict__ iouT,
    const float* __restrict__ fxT,
    const float* __restrict__ fscT,
    const float* __restrict__ W_iouh,
    const float* __restrict__ W_fh,
    unsigned* __restrict__ hplane,
    float* __restrict__ out)             // [16384][512]
{
  const int wg = blockIdx.x, bg = wg >> 4, gm = wg & 15;
  const int m0 = gm * 32, B0 = bg * 16;
  const int tid = threadIdx.x, lane = tid & 63, wv = tid >> 6;
  const int gate = wv & 3, half = wv >> 2;

  // ---- persistent weight fragments: 16 rows (m0+half*16+arow) of `gate` ----
  const int arow = lane & 15, kgrp = lane >> 4;
  const int mrow = m0 + half * 16 + arow;
  const float* wrow = (gate < 3) ? (W_iouh + (size_t)(gate * MEM + mrow) * MEM)
                                 : (W_fh   + (size_t)mrow * MEM);
  bf16x8 Ahi[16], Alo[16];
#pragma unroll
  for (int kt = 0; kt < 16; ++kt) {
    const float* wp = wrow + kt * 32 + kgrp * 8;
    bf16x8 hi, lo;
#pragma unroll
    for (int e = 0; e < 8; ++e) {
      float w = wp[e];
      short h16 = f2bf(w);
      hi[e] = h16;
      lo[e] = f2bf(w - bf2f(h16));
    }
    Ahi[kt] = hi; Alo[kt] = lo;
  }

  __shared__ __align__(16) unsigned short BhiL[16][520];
  __shared__ __align__(16) unsigned short BloL[16][520];
  __shared__ float preT[128 * 18];     // [gate*32+m_local][b], stride 18
  __shared__ unsigned hT[16 * 33];     // [b][mj] packed+tagged h
  __shared__ int rdy[2][8];

  unsigned* const hbase = hplane + (size_t)bg * 8192;   // + buf*32768

  // combine mapping: thread -> (b8 = tid&15, mj = tid>>4 in [0,32))
  const int b8 = tid & 15, mj = tid >> 4;
  const int m = m0 + mj;
  const float* p_i = iouT + (size_t)m * ROWS;
  const float* p_o = iouT + (size_t)(MEM + m) * ROWS;
  const float* p_u = iouT + (size_t)(2 * MEM + m) * ROWS;
  const float* p_f = fxT  + (size_t)m * ROWS;
  const float* p_s = fscT + (size_t)m * ROWS;

  // stage mapping: thread -> 16 dwords at plane index tid*16 (b=tid>>5)
  const int sb = tid >> 5;                 // batch row staged
  const int smc = (tid & 31) * 16;         // m-col base staged
  const bool ownSlice = (((tid & 31) >> 1) == gm);
  const int ownOff = ((tid & 31) & 1) * 16;  // 0 or 16 within own 32-m slice

  const int bb = lane & 15;
  float c_reg = 0.f;

  for (int t = 0; t < T_STEPS; ++t) {
    const int rb = t & 1;
    const unsigned rtag = (unsigned)((t >> 1) & 1);
    const int row = t * BATCH + B0 + b8;
    // pre-activation streams: issued first, consumed ~1us later in combine
    float ip = p_i[row], op = p_o[row], up = p_u[row], fp = p_f[row], sv = p_s[row];

    // ---- poll-stage: load tagged h dwords until all valid ----
    const unsigned* hPr = hbase + (size_t)rb * 32768;
    u32x4 C[4];
    int ok0, ok1, ok2, ok3;
    if (ownSlice && t > 0) {
      // own m-slice: take from hT (written by our own publish last step)
#pragma unroll
      for (int j = 0; j < 4; ++j)
#pragma unroll
        for (int d = 0; d < 4; ++d)
          C[j][d] = hT[sb * 33 + ownOff + j * 4 + d];
      ok0 = ok1 = ok2 = ok3 = 1;
    } else {
      ok0 = ok1 = ok2 = ok3 = 0;
    }
    int iterp = 0;
    for (;;) {
      if (!ok0) C[0] = load16_sc(hPr + tid * 16 + 0);
      if (!ok1) C[1] = load16_sc(hPr + tid * 16 + 4);
      if (!ok2) C[2] = load16_sc(hPr + tid * 16 + 8);
      if (!ok3) C[3] = load16_sc(hPr + tid * 16 + 12);
      asm volatile("s_waitcnt vmcnt(0)" ::: "memory");
#define TAGOK(c) ((((c[0] ^ rtag) | (c[1] ^ rtag) | (c[2] ^ rtag) | (c[3] ^ rtag)) & 1u) == 0u)
      ok0 = ok0 || TAGOK(C[0]);
      ok1 = ok1 || TAGOK(C[1]);
      ok2 = ok2 || TAGOK(C[2]);
      ok3 = ok3 || TAGOK(C[3]);
#undef TAGOK
      int wall = __all(ok0 & ok1 & ok2 & ok3);
      if (lane == 0) rdy[iterp][wv] = wall;
      __syncthreads();
      int g = rdy[iterp][0] & rdy[iterp][1] & rdy[iterp][2] & rdy[iterp][3] &
              rdy[iterp][4] & rdy[iterp][5] & rdy[iterp][6] & rdy[iterp][7];
      iterp ^= 1;
      if (g) break;
    }
    // unpack staged dwords -> LDS hi/lo tiles
#pragma unroll
    for (int j = 0; j < 4; ++j) {
      u32x4 c = C[j];
      short4v hi4 = {(short)(c[0] >> 16), (short)(c[1] >> 16),
                     (short)(c[2] >> 16), (short)(c[3] >> 16)};
      short4v lo4 = {(short)(c[0] & 0xffff), (short)(c[1] & 0xffff),
                     (short)(c[2] & 0xffff), (short)(c[3] & 0xffff)};
      *(short4v*)&BhiL[sb][smc + j * 4] = hi4;
      *(short4v*)&BloL[sb][smc + j * 4] = lo4;
    }
    __syncthreads();

    // ---- MFMA: 16 kt x 3 split products, 4 interleaved acc chains ----
    f32x4 acc[4] = {{0.f,0.f,0.f,0.f},{0.f,0.f,0.f,0.f},{0.f,0.f,0.f,0.f},{0.f,0.f,0.f,0.f}};
#pragma unroll
    for (int kt = 0; kt < 16; ++kt) {
      bf16x8 bhiF = *(const bf16x8*)&BhiL[bb][kt * 32 + kgrp * 8];
      bf16x8 bloF = *(const bf16x8*)&BloL[bb][kt * 32 + kgrp * 8];
      acc[(3 * kt + 0) & 3] = __builtin_amdgcn_mfma_f32_16x16x32_bf16(Ahi[kt], bhiF, acc[(3 * kt + 0) & 3], 0, 0, 0);
      acc[(3 * kt + 1) & 3] = __builtin_amdgcn_mfma_f32_16x16x32_bf16(Ahi[kt], bloF, acc[(3 * kt + 1) & 3], 0, 0, 0);
      acc[(3 * kt + 2) & 3] = __builtin_amdgcn_mfma_f32_16x16x32_bf16(Alo[kt], bhiF, acc[(3 * kt + 2) & 3], 0, 0, 0);
    }
    f32x4 accs = (acc[0] + acc[1]) + (acc[2] + acc[3]);
    // D: col = lane&15 (=bb = batch), row r = kgrp*4+i -> m_local = half*16+r
#pragma unroll
    for (int i = 0; i < 4; ++i)
      preT[(gate * 32 + half * 16 + kgrp * 4 + i) * 18 + bb] = accs[i];
    __syncthreads();

    // ---- combine ----
    float pi = ip + preT[(0  + mj) * 18 + b8];
    float po = op + preT[(32 + mj) * 18 + b8];
    float pu = up + preT[(64 + mj) * 18 + b8];
    float pf = fp + preT[(96 + mj) * 18 + b8];
    float ig = sigmoidf_(pi);
    float og = sigmoidf_(po);
    float ug = tanhf(pu);
    float fg = sigmoidf_(pf);
    float cc = ig * ug + fg * c_reg + sv;
    float hv = og * tanhf(cc);
    c_reg = cc;

    if (t < T_STEPS - 1) {
      // ---- publish: pack + epoch-tag, LDS transpose, coalesced sc stores ----
      const unsigned wtag = (unsigned)(((t + 1) >> 1) & 1);
      short h16 = f2bf(hv);
      short l16 = f2bf(hv - bf2f(h16));
      unsigned hu = ((unsigned)(unsigned short)h16 << 16)
                  | ((unsigned)(unsigned short)l16 & 0xFFFEu) | wtag;
      hT[b8 * 33 + mj] = hu;
      __syncthreads();
      {
        int psb = tid >> 5, psm = tid & 31;
        unsigned v = hT[psb * 33 + psm];
        unsigned* hPw = hbase + (size_t)(rb ^ 1) * 32768;
        store4_sc(hPw + psb * 512 + m0 + psm, v);   // fire-and-forget
      }
    }
    // out store off the critical path (plain cached store)
    out[(size_t)row * MEM + m] = hv;
  }
}

// ---------------------------------------------------------------------------
extern "C" void kernel_launch(void* const* d_in, const int* in_sizes, int n_in,
                              void* d_out, int out_size, void* d_ws, size_t ws_size,
                              hipStream_t stream) {
  const float* inputs   = (const float*)d_in[0];
  const float* sememe_c = (const float*)d_in[1];
  const float* sememe_h = (const float*)d_in[2];
  const float* W_ioux   = (const float*)d_in[3];
  const float* b_ioux   = (const float*)d_in[4];
  const float* W_iouh   = (const float*)d_in[5];
  const float* b_iouh   = (const float*)d_in[6];
  const float* W_ious   = (const float*)d_in[7];
  const float* b_ious   = (const float*)d_in[8];
  const float* W_fx     = (const float*)d_in[9];
  const float* b_fx     = (const float*)d_in[10];
  const float* W_fxs    = (const float*)d_in[11];
  const float* b_fxs    = (const float*)d_in[12];
  const float* W_fh     = (const float*)d_in[13];
  const float* b_fh     = (const float*)d_in[14];
  const float* W_fs     = (const float*)d_in[15];
  const float* b_fs     = (const float*)d_in[16];

  float* iouT = (float*)d_ws;                             // [1536][16384] f32
  float* fxT  = iouT + (size_t)1536 * ROWS;               // [512][16384]
  float* fscT = fxT  + (size_t)512 * ROWS;                // [512][16384]
  char*  Apack = (char*)(fscT + (size_t)512 * ROWS);      // 67,108,864 B
  char*  Wpack = Apack + (size_t)128 * 32 * 128 * 128;    // 10,485,760 B
  unsigned* hplane = (unsigned*)(Wpack + (size_t)20 * 32 * 128 * 128);  // 2*4*8192 dwords

  // buf0 (dwords 0..32767): 0x00 -> valid h0=0 with tag 0.
  // buf1 (dwords 32768..65535): 0x01010101 -> stale-marked (tag 1 != tau(1)=0).
  hipMemsetAsync(hplane,         0x00, 32768 * 4, stream);
  hipMemsetAsync(hplane + 32768, 0x01, 32768 * 4, stream);

  pack_act<<<dim3(8192), dim3(256), 0, stream>>>(inputs, sememe_h, Apack);
  pack_w<<<dim3(1280), dim3(256), 0, stream>>>(W_ioux, W_ious, W_fx, W_fxs, W_fs, Wpack);

  gemm_mfma<<<dim3(2560), dim3(256), 0, stream>>>(
      Apack, Wpack, sememe_c,
      b_ioux, b_iouh, b_ious, b_fx, b_fh, b_fxs, b_fs,
      iouT, fxT, fscT);

  lstm_rec<<<dim3(64), dim3(512), 0, stream>>>(
      iouT, fxT, fscT, W_iouh, W_fh, hplane, (float*)d_out);
}